// Round 1
// baseline (826.217 us; speedup 1.0000x reference)
//
#include <hip/hip_runtime.h>
#include <hip/hip_bf16.h>
#include <math.h>

// Shapes: B=1, S=512, N=384, c_m=64, c_z=128, H=8, c=32  (HC = 256)
//
// Pipeline:
//  k0_w4t : W4[256,64] fp32 -> W4t[64][256] bf16 (for MFMA B-frags)
//  k1     : m = LN(m_si); v = m@W1 -> v_tg[s][h][c][j] bf16 (transposed!);
//           g = sigmoid(m@W3) -> g_bf[s][j][hc] bf16.  16 rows/block.
//  k2     : b = LN(z)@W2 -> w_buf[h][i][j] fp32   (64 rows/block, fold-reduce)
//  k3a    : partial online softmax (m,l) per (h, 16-i-chunk, j)
//  k3m    : combine 24 partials -> M[h][j], invL[h][j]
//  k3b    : w_bf[h][i][j] = bf16( exp(x - M) * invL )
//  k4     : MFMA: per (s, 64-i-tile): for h: O[64,32] = W_h[64,384]@V_sh[384,32],
//           gate, collect o_l[64][256] bf16 in LDS, then out = o_l @ W4 (MFMA).
//           V B-fragments read DIRECTLY from global (v_tg layout == fragment
//           layout) -> no V staging, no barriers, 4 blocks/CU.

typedef __attribute__((ext_vector_type(8))) short bf16x8;   // 8 bf16 = 4 VGPRs
typedef __attribute__((ext_vector_type(4))) float f32x4;

__global__ __launch_bounds__(256) void k0_w4t(
    const float* __restrict__ W4, __hip_bfloat16* __restrict__ W4t)
{
    int idx = blockIdx.x * 256 + threadIdx.x;   // 64*256 = 16384
    int d = idx >> 8, k = idx & 255;
    W4t[idx] = __float2bfloat16(W4[k * 64 + d]);
}

// ---------------------------------------------------------------------------
// k1: 16 rows (j's) of one s per block. grid = 512*24 = 12288, block 256.
__global__ __launch_bounds__(256) void k1_ln_mv(
    const float* __restrict__ m_si,
    const float* __restrict__ gamma_m, const float* __restrict__ beta_m,
    const float* __restrict__ W1, const float* __restrict__ W3,
    __hip_bfloat16* __restrict__ v_tg,   // [512][8][32][384]
    __hip_bfloat16* __restrict__ g_bf)   // [512][384][256]
{
    const int bx = blockIdx.x;
    const int s = bx / 24, j0 = (bx % 24) * 16;
    const int tid = threadIdx.x;
    const int lane = tid & 63, wv = tid >> 6;
    __shared__ float mhat[16][64];

    const float* mrow = m_si + (size_t)(s * 384 + j0) * 64;
    #pragma unroll
    for (int rr = 0; rr < 4; rr++) {
        int r = wv * 4 + rr;
        float x = mrow[r * 64 + lane];
        float s1 = x, s2 = x * x;
        #pragma unroll
        for (int off = 32; off > 0; off >>= 1) {
            s1 += __shfl_xor(s1, off, 64);
            s2 += __shfl_xor(s2, off, 64);
        }
        float mu  = s1 * (1.0f / 64.0f);
        float var = s2 * (1.0f / 64.0f) - mu * mu;
        float rs  = rsqrtf(var + 1e-5f);
        mhat[r][lane] = (x - mu) * rs * gamma_m[lane] + beta_m[lane];
    }
    __syncthreads();

    const int co = tid;
    float a1[16], a3[16];
    #pragma unroll
    for (int r = 0; r < 16; r++) { a1[r] = 0.f; a3[r] = 0.f; }
    for (int k = 0; k < 64; k += 4) {
        float w1a = W1[(k    ) * 256 + co], w3a = W3[(k    ) * 256 + co];
        float w1b = W1[(k + 1) * 256 + co], w3b = W3[(k + 1) * 256 + co];
        float w1c = W1[(k + 2) * 256 + co], w3c = W3[(k + 2) * 256 + co];
        float w1d = W1[(k + 3) * 256 + co], w3d = W3[(k + 3) * 256 + co];
        #pragma unroll
        for (int r = 0; r < 16; r++) {
            float4 m4 = *(const float4*)&mhat[r][k];   // broadcast b128
            a1[r] = fmaf(m4.x, w1a, a1[r]); a1[r] = fmaf(m4.y, w1b, a1[r]);
            a1[r] = fmaf(m4.z, w1c, a1[r]); a1[r] = fmaf(m4.w, w1d, a1[r]);
            a3[r] = fmaf(m4.x, w3a, a3[r]); a3[r] = fmaf(m4.y, w3b, a3[r]);
            a3[r] = fmaf(m4.z, w3c, a3[r]); a3[r] = fmaf(m4.w, w3d, a3[r]);
        }
    }

    #pragma unroll
    for (int r = 0; r < 16; r++) {
        float g = 1.0f / (1.0f + __expf(-a3[r]));
        g_bf[(size_t)(s * 384 + j0 + r) * 256 + co] = __float2bfloat16(g);
    }
    bf16x8 lo, hi;
    #pragma unroll
    for (int r = 0; r < 8; r++) {
        __hip_bfloat16 b0 = __float2bfloat16(a1[r]);
        __hip_bfloat16 b1 = __float2bfloat16(a1[r + 8]);
        lo[r] = *(short*)&b0;
        hi[r] = *(short*)&b1;
    }
    short* vp = (short*)v_tg + (size_t)s * 98304 + co * 384 + j0;
    *(bf16x8*)vp = lo;
    *(bf16x8*)(vp + 8) = hi;
}

// ---------------------------------------------------------------------------
// k2: 64 rows/block, 4 waves, one wave per row step. grid = 2304.
__global__ __launch_bounds__(256) void k2_ln_z(
    const float* __restrict__ z,
    const float* __restrict__ gamma_z, const float* __restrict__ beta_z,
    const float* __restrict__ W2, float* __restrict__ b_buf)
{
    const int tid = threadIdx.x;
    const int lane = tid & 63, wv = tid >> 6;
    const int R0 = blockIdx.x * 64;
    __shared__ float part[64][9];       // [row_local][h], stride 9 = conflict-free

    // per-lane constants: k-pair 2*lane, 2*lane+1
    float2 g2 = *(const float2*)&gamma_z[lane * 2];
    float2 be2 = *(const float2*)&beta_z[lane * 2];
    float4 w2a = *(const float4*)&W2[lane * 16];       // W2[2*lane][0..3]
    float4 w2b = *(const float4*)&W2[lane * 16 + 4];   // W2[2*lane][4..7]
    float4 w2c = *(const float4*)&W2[lane * 16 + 8];   // W2[2*lane+1][0..3]
    float4 w2d = *(const float4*)&W2[lane * 16 + 12];  // W2[2*lane+1][4..7]

    const bool hi4 = (lane & 4) != 0;
    const bool hi2 = (lane & 2) != 0;
    const bool hi1 = (lane & 1) != 0;

    float2 zx = *(const float2*)&z[(size_t)(R0 + wv * 16) * 128 + lane * 2];
    #pragma unroll 1
    for (int rr = 0; rr < 16; rr++) {
        const int rl = wv * 16 + rr;
        float x0 = zx.x, x1 = zx.y;
        if (rr < 15)
            zx = *(const float2*)&z[(size_t)(R0 + rl + 1) * 128 + lane * 2];

        float s1 = x0 + x1, s2 = x0 * x0 + x1 * x1;
        #pragma unroll
        for (int off = 32; off > 0; off >>= 1) {
            s1 += __shfl_xor(s1, off, 64);
            s2 += __shfl_xor(s2, off, 64);
        }
        float mu  = s1 * (1.0f / 128.0f);
        float var = s2 * (1.0f / 128.0f) - mu * mu;
        float rs  = rsqrtf(var + 1e-5f);
        float mh0 = (x0 - mu) * rs * g2.x + be2.x;
        float mh1 = (x1 - mu) * rs * g2.y + be2.y;

        float p[8];
        p[0] = fmaf(mh0, w2a.x, mh1 * w2c.x);
        p[1] = fmaf(mh0, w2a.y, mh1 * w2c.y);
        p[2] = fmaf(mh0, w2a.z, mh1 * w2c.z);
        p[3] = fmaf(mh0, w2a.w, mh1 * w2c.w);
        p[4] = fmaf(mh0, w2b.x, mh1 * w2d.x);
        p[5] = fmaf(mh0, w2b.y, mh1 * w2d.y);
        p[6] = fmaf(mh0, w2b.z, mh1 * w2d.z);
        p[7] = fmaf(mh0, w2b.w, mh1 * w2d.w);

        // fold: value-split on lane bits 2,1,0 -> h = lane&7
        float t[4];
        #pragma unroll
        for (int k = 0; k < 4; k++) {
            float keep = hi4 ? p[k + 4] : p[k];
            float send = hi4 ? p[k] : p[k + 4];
            t[k] = keep + __shfl_xor(send, 4, 64);
        }
        float u[2];
        #pragma unroll
        for (int k = 0; k < 2; k++) {
            float keep = hi2 ? t[k + 2] : t[k];
            float send = hi2 ? t[k] : t[k + 2];
            u[k] = keep + __shfl_xor(send, 2, 64);
        }
        float vsum;
        {
            float keep = hi1 ? u[1] : u[0];
            float send = hi1 ? u[0] : u[1];
            vsum = keep + __shfl_xor(send, 1, 64);
        }
        vsum += __shfl_xor(vsum, 8, 64);
        vsum += __shfl_xor(vsum, 16, 64);
        vsum += __shfl_xor(vsum, 32, 64);
        if (lane < 8) part[rl][lane] = vsum;   // h = lane
    }
    __syncthreads();

    // write: 512 outputs, thread t writes (h=t>>6, rl=t&63) and (h+4, rl)
    {
        int h0 = tid >> 6, rl = tid & 63;
        b_buf[(size_t)h0 * 147456 + R0 + rl]       = part[rl][h0];
        b_buf[(size_t)(h0 + 4) * 147456 + R0 + rl] = part[rl][h0 + 4];
    }
}

// ---------------------------------------------------------------------------
// k3a: partial online softmax over 16-i chunks. grid = 8*24 = 192, block 128.
__global__ __launch_bounds__(128) void k3a_part(
    const float* __restrict__ w_buf, float* __restrict__ pm, float* __restrict__ pl)
{
    const int h = blockIdx.x / 24, ic = blockIdx.x % 24;
    const int i0 = ic * 16;
    const int tid = threadIdx.x;
    const float* base = w_buf + ((size_t)h * 384 + i0) * 384;

    float m0 = -INFINITY, m1 = -INFINITY, m2 = -INFINITY;
    float l0 = 0.f, l1 = 0.f, l2 = 0.f;
    #pragma unroll 4
    for (int ii = 0; ii < 16; ii++) {
        float x0 = base[ii * 384 + tid];
        float x1 = base[ii * 384 + tid + 128];
        float x2 = base[ii * 384 + tid + 256];
        float n0 = fmaxf(m0, x0);
        l0 = l0 * __expf(m0 - n0) + __expf(x0 - n0); m0 = n0;
        float n1 = fmaxf(m1, x1);
        l1 = l1 * __expf(m1 - n1) + __expf(x1 - n1); m1 = n1;
        float n2 = fmaxf(m2, x2);
        l2 = l2 * __expf(m2 - n2) + __expf(x2 - n2); m2 = n2;
    }
    float* pmb = pm + ((size_t)h * 24 + ic) * 384;
    float* plb = pl + ((size_t)h * 24 + ic) * 384;
    pmb[tid]       = m0;  plb[tid]       = l0;
    pmb[tid + 128] = m1;  plb[tid + 128] = l1;
    pmb[tid + 256] = m2;  plb[tid + 256] = l2;
}

// k3m: combine 24 partials -> M, invL. grid = 8 blocks, 384 threads.
__global__ __launch_bounds__(384) void k3m_comb(
    const float* __restrict__ pm, const float* __restrict__ pl,
    float* __restrict__ Mf, float* __restrict__ invLf)
{
    const int h = blockIdx.x, j = threadIdx.x;
    float M = -INFINITY, L = 0.f;
    #pragma unroll 4
    for (int ic = 0; ic < 24; ic++) {
        float m = pm[((size_t)h * 24 + ic) * 384 + j];
        float l = pl[((size_t)h * 24 + ic) * 384 + j];
        float nM = fmaxf(M, m);
        L = L * __expf(M - nM) + l * __expf(m - nM);
        M = nM;
    }
    Mf[h * 384 + j] = M;
    invLf[h * 384 + j] = 1.0f / L;
}

// k3b: write normalized bf16 weights. grid = 192, block 128.
__global__ __launch_bounds__(128) void k3b_write(
    const float* __restrict__ w_buf, const float* __restrict__ Mf,
    const float* __restrict__ invLf, __hip_bfloat16* __restrict__ w_bf)
{
    const int h = blockIdx.x / 24, ic = blockIdx.x % 24;
    const int i0 = ic * 16;
    const int tid = threadIdx.x;
    const float* base = w_buf + ((size_t)h * 384 + i0) * 384;
    __hip_bfloat16* ob = w_bf + ((size_t)h * 384 + i0) * 384;

    float M0 = Mf[h * 384 + tid],       iL0 = invLf[h * 384 + tid];
    float M1 = Mf[h * 384 + tid + 128], iL1 = invLf[h * 384 + tid + 128];
    float M2 = Mf[h * 384 + tid + 256], iL2 = invLf[h * 384 + tid + 256];
    #pragma unroll 4
    for (int ii = 0; ii < 16; ii++) {
        float x0 = base[ii * 384 + tid];
        float x1 = base[ii * 384 + tid + 128];
        float x2 = base[ii * 384 + tid + 256];
        ob[ii * 384 + tid]       = __float2bfloat16(__expf(x0 - M0) * iL0);
        ob[ii * 384 + tid + 128] = __float2bfloat16(__expf(x1 - M1) * iL1);
        ob[ii * 384 + tid + 256] = __float2bfloat16(__expf(x2 - M2) * iL2);
    }
}

// ---------------------------------------------------------------------------
// k4: MFMA einsum + gate + @W4.  grid = 512*6 = 3072 blocks, 256 threads.
//
// Restructured (this round): V B-fragments are read DIRECTLY from global —
// v_tg's [s][h][c][j] layout IS the MFMA B-fragment layout (lane(col,quad)
// reads v[h][col][k0+quad*8..+8] as one 16B load). All 4 waves read identical
// fragments -> L1 broadcast. This deletes the v_t LDS buffer and BOTH per-h
// barriers. o_l is per-wave private (wave wv writes rows [wv*16,wv*16+16) and
// the final W4 matmul reads exactly those rows), so the kernel needs ZERO
// __syncthreads. LDS 58880 -> 33792 B => 4 blocks/CU (16 waves/CU).
// Bijective XCD swizzle (3072 = 8*384): the 6 i-tiles of one s run on one
// XCD concurrently and share its 196KB V slab in that XCD's L2.
#define OSTR 264   // LDS o_l stride: 528 B -> superbank step = 33 % 8 = 1

__global__ __launch_bounds__(256, 4) void k4_mfma(
    const __hip_bfloat16* __restrict__ w_bf,   // [8][384][384]
    const __hip_bfloat16* __restrict__ v_tg,   // [512][8][32][384]
    const __hip_bfloat16* __restrict__ g_bf,   // [512][384][256]
    const __hip_bfloat16* __restrict__ W4t,    // [64][256]
    float* __restrict__ out)                   // [512][384][64]
{
    __shared__ short o_l[64 * OSTR];           // 33792 B
    const int bx0 = blockIdx.x;
    const int bx = (bx0 & 7) * 384 + (bx0 >> 3);   // bijective XCD swizzle
    const int s = bx / 6, i0 = (bx % 6) * 64;
    const int tid = threadIdx.x;
    const int lane = tid & 63, wv = tid >> 6;
    const int col = lane & 15, quad = lane >> 4;

    const short* wA_base = (const short*)w_bf
        + (size_t)(i0 + wv * 16 + col) * 384 + quad * 8;
    const short* vbase = (const short*)v_tg
        + (size_t)s * 98304 + col * 384 + quad * 8;
    const __hip_bfloat16* gbase = g_bf + (size_t)(s * 384 + i0) * 256;
    const int ibase = wv * 16 + quad * 4;

    #pragma unroll 1
    for (int h = 0; h < 8; h++) {
        // hoist gate loads above the MFMA loop: latency hides under MFMA
        float g0[4], g1[4];
        #pragma unroll
        for (int reg = 0; reg < 4; reg++) {
            int il = ibase + reg;
            g0[reg] = __bfloat162float(gbase[il * 256 + h * 32 + col]);
            g1[reg] = __bfloat162float(gbase[il * 256 + h * 32 + 16 + col]);
        }

        f32x4 acc0 = {0.f, 0.f, 0.f, 0.f}, acc1 = {0.f, 0.f, 0.f, 0.f};
        const short* wA = wA_base + (size_t)h * 147456;
        const short* vh = vbase + h * 12288;
        #pragma unroll
        for (int ks = 0; ks < 12; ks++) {
            int k0 = ks * 32;
            bf16x8 a  = *(const bf16x8*)(wA + k0);
            bf16x8 b0 = *(const bf16x8*)(vh + k0);              // c = col
            bf16x8 b1 = *(const bf16x8*)(vh + 16 * 384 + k0);   // c = 16+col
            acc0 = __builtin_amdgcn_mfma_f32_16x16x32_bf16(a, b0, acc0, 0, 0, 0);
            acc1 = __builtin_amdgcn_mfma_f32_16x16x32_bf16(a, b1, acc1, 0, 0, 0);
        }
        #pragma unroll
        for (int reg = 0; reg < 4; reg++) {
            int il = ibase + reg;
            __hip_bfloat16 t0 = __float2bfloat16(acc0[reg] * g0[reg]);
            __hip_bfloat16 t1 = __float2bfloat16(acc1[reg] * g1[reg]);
            o_l[il * OSTR + h * 32 + col]      = *(short*)&t0;
            o_l[il * OSTR + h * 32 + 16 + col] = *(short*)&t1;
        }
    }

    // final: out[64,64] = o_l[64,256] @ W4t^T — o_l rows are per-wave private,
    // no barrier needed (within-wave ds_write->ds_read ordered by lgkmcnt).
    f32x4 acc2[4];
    #pragma unroll
    for (int n = 0; n < 4; n++) acc2[n] = (f32x4){0.f, 0.f, 0.f, 0.f};
    #pragma unroll
    for (int ks = 0; ks < 8; ks++) {
        int k0 = ks * 32;
        bf16x8 a = *(const bf16x8*)&o_l[(wv * 16 + col) * OSTR + k0 + quad * 8];
        #pragma unroll
        for (int n = 0; n < 4; n++) {
            bf16x8 b = *(const bf16x8*)((const short*)W4t
                        + (n * 16 + col) * 256 + k0 + quad * 8);
            acc2[n] = __builtin_amdgcn_mfma_f32_16x16x32_bf16(a, b, acc2[n], 0, 0, 0);
        }
    }
    float* obase = out + (size_t)(s * 384 + i0 + wv * 16 + quad * 4) * 64;
    #pragma unroll
    for (int n = 0; n < 4; n++)
        #pragma unroll
        for (int reg = 0; reg < 4; reg++)
            obase[reg * 64 + n * 16 + col] = acc2[n][reg];
}

// ---------------------------------------------------------------------------
extern "C" void kernel_launch(void* const* d_in, const int* in_sizes, int n_in,
                              void* d_out, int out_size, void* d_ws, size_t ws_size,
                              hipStream_t stream)
{
    const float* m_si    = (const float*)d_in[0];
    const float* z_ij    = (const float*)d_in[1];
    const float* gamma_m = (const float*)d_in[2];
    const float* beta_m  = (const float*)d_in[3];
    const float* W1      = (const float*)d_in[4];
    const float* gamma_z = (const float*)d_in[5];
    const float* beta_z  = (const float*)d_in[6];
    const float* W2      = (const float*)d_in[7];
    const float* W3      = (const float*)d_in[8];
    const float* W4      = (const float*)d_in[9];
    float* out = (float*)d_out;

    // ws layout (~209.0 MB):
    //   g_bf : 100663296 B   v_tg : 100663296 B   w_buf(fp32): 4718592 B
    //   w_bf : 2359296 B     W4t  : 32768 B
    //   pm/pl: 294912 B each   Mf/invLf: 12288 B each
    char* ws = (char*)d_ws;
    __hip_bfloat16* g_bf = (__hip_bfloat16*)ws;
    __hip_bfloat16* v_tg = (__hip_bfloat16*)(ws + 100663296);
    float*          w_buf = (float*)(ws + 201326592);
    __hip_bfloat16* w_bf = (__hip_bfloat16*)(ws + 206045184);
    __hip_bfloat16* W4t  = (__hip_bfloat16*)(ws + 208404480);
    float* pm    = (float*)(ws + 208437248);
    float* pl    = (float*)(ws + 208732160);
    float* Mf    = (float*)(ws + 209027072);
    float* invLf = (float*)(ws + 209039360);

    k0_w4t   <<<64,    256, 0, stream>>>(W4, W4t);
    k1_ln_mv <<<12288, 256, 0, stream>>>(m_si, gamma_m, beta_m, W1, W3, v_tg, g_bf);
    k2_ln_z  <<<2304,  256, 0, stream>>>(z_ij, gamma_z, beta_z, W2, w_buf);
    k3a_part <<<192,   128, 0, stream>>>(w_buf, pm, pl);
    k3m_comb <<<8,     384, 0, stream>>>(pm, pl, Mf, invLf);
    k3b_write<<<192,   128, 0, stream>>>(w_buf, Mf, invLf, w_bf);
    k4_mfma  <<<3072,  256, 0, stream>>>(w_bf, v_tg, g_bf, W4t, out);
}

// Round 2
// 632.595 us; speedup vs baseline: 1.3061x; 1.3061x over previous
//
#include <hip/hip_runtime.h>
#include <hip/hip_bf16.h>
#include <math.h>

// Shapes: B=1, S=512, N=384, c_m=64, c_z=128, H=8, c=32  (HC = 256)
//
// Pipeline:
//  k0_w4t : W4[256,64] fp32 -> W4t[64][256] bf16 (for MFMA B-frags)
//  k1     : m = LN(m_si); v = m@W1 -> v_tg[s][h][c][j] bf16 (transposed!);
//           g = sigmoid(m@W3) -> g_bf[s][j][hc] bf16.  16 rows/block.
//  k2     : b = LN(z)@W2 -> w_buf[h][i][j] fp32   (64 rows/block, fold-reduce)
//  k3a    : partial online softmax (m,l) per (h, 16-i-chunk, j)
//  k3m    : combine 24 partials -> M[h][j], invL[h][j]
//  k3b    : w_bf[h][i][j] = bf16( exp(x - M) * invL )
//  k4     : MFMA einsum + gate + @W4, async-pipelined V staging (see k4).

typedef __attribute__((ext_vector_type(8))) short bf16x8;   // 8 bf16 = 4 VGPRs
typedef __attribute__((ext_vector_type(4))) float f32x4;
typedef unsigned int u32;

__global__ __launch_bounds__(256) void k0_w4t(
    const float* __restrict__ W4, __hip_bfloat16* __restrict__ W4t)
{
    int idx = blockIdx.x * 256 + threadIdx.x;   // 64*256 = 16384
    int d = idx >> 8, k = idx & 255;
    W4t[idx] = __float2bfloat16(W4[k * 64 + d]);
}

// ---------------------------------------------------------------------------
// k1: 16 rows (j's) of one s per block. grid = 512*24 = 12288, block 256.
__global__ __launch_bounds__(256) void k1_ln_mv(
    const float* __restrict__ m_si,
    const float* __restrict__ gamma_m, const float* __restrict__ beta_m,
    const float* __restrict__ W1, const float* __restrict__ W3,
    __hip_bfloat16* __restrict__ v_tg,   // [512][8][32][384]
    __hip_bfloat16* __restrict__ g_bf)   // [512][384][256]
{
    const int bx = blockIdx.x;
    const int s = bx / 24, j0 = (bx % 24) * 16;
    const int tid = threadIdx.x;
    const int lane = tid & 63, wv = tid >> 6;
    __shared__ float mhat[16][64];

    const float* mrow = m_si + (size_t)(s * 384 + j0) * 64;
    #pragma unroll
    for (int rr = 0; rr < 4; rr++) {
        int r = wv * 4 + rr;
        float x = mrow[r * 64 + lane];
        float s1 = x, s2 = x * x;
        #pragma unroll
        for (int off = 32; off > 0; off >>= 1) {
            s1 += __shfl_xor(s1, off, 64);
            s2 += __shfl_xor(s2, off, 64);
        }
        float mu  = s1 * (1.0f / 64.0f);
        float var = s2 * (1.0f / 64.0f) - mu * mu;
        float rs  = rsqrtf(var + 1e-5f);
        mhat[r][lane] = (x - mu) * rs * gamma_m[lane] + beta_m[lane];
    }
    __syncthreads();

    const int co = tid;
    float a1[16], a3[16];
    #pragma unroll
    for (int r = 0; r < 16; r++) { a1[r] = 0.f; a3[r] = 0.f; }
    for (int k = 0; k < 64; k += 4) {
        float w1a = W1[(k    ) * 256 + co], w3a = W3[(k    ) * 256 + co];
        float w1b = W1[(k + 1) * 256 + co], w3b = W3[(k + 1) * 256 + co];
        float w1c = W1[(k + 2) * 256 + co], w3c = W3[(k + 2) * 256 + co];
        float w1d = W1[(k + 3) * 256 + co], w3d = W3[(k + 3) * 256 + co];
        #pragma unroll
        for (int r = 0; r < 16; r++) {
            float4 m4 = *(const float4*)&mhat[r][k];   // broadcast b128
            a1[r] = fmaf(m4.x, w1a, a1[r]); a1[r] = fmaf(m4.y, w1b, a1[r]);
            a1[r] = fmaf(m4.z, w1c, a1[r]); a1[r] = fmaf(m4.w, w1d, a1[r]);
            a3[r] = fmaf(m4.x, w3a, a3[r]); a3[r] = fmaf(m4.y, w3b, a3[r]);
            a3[r] = fmaf(m4.z, w3c, a3[r]); a3[r] = fmaf(m4.w, w3d, a3[r]);
        }
    }

    #pragma unroll
    for (int r = 0; r < 16; r++) {
        float g = 1.0f / (1.0f + __expf(-a3[r]));
        g_bf[(size_t)(s * 384 + j0 + r) * 256 + co] = __float2bfloat16(g);
    }
    bf16x8 lo, hi;
    #pragma unroll
    for (int r = 0; r < 8; r++) {
        __hip_bfloat16 b0 = __float2bfloat16(a1[r]);
        __hip_bfloat16 b1 = __float2bfloat16(a1[r + 8]);
        lo[r] = *(short*)&b0;
        hi[r] = *(short*)&b1;
    }
    short* vp = (short*)v_tg + (size_t)s * 98304 + co * 384 + j0;
    *(bf16x8*)vp = lo;
    *(bf16x8*)(vp + 8) = hi;
}

// ---------------------------------------------------------------------------
// k2: 64 rows/block, 4 waves, one wave per row step. grid = 2304.
__global__ __launch_bounds__(256) void k2_ln_z(
    const float* __restrict__ z,
    const float* __restrict__ gamma_z, const float* __restrict__ beta_z,
    const float* __restrict__ W2, float* __restrict__ b_buf)
{
    const int tid = threadIdx.x;
    const int lane = tid & 63, wv = tid >> 6;
    const int R0 = blockIdx.x * 64;
    __shared__ float part[64][9];       // [row_local][h], stride 9 = conflict-free

    // per-lane constants: k-pair 2*lane, 2*lane+1
    float2 g2 = *(const float2*)&gamma_z[lane * 2];
    float2 be2 = *(const float2*)&beta_z[lane * 2];
    float4 w2a = *(const float4*)&W2[lane * 16];       // W2[2*lane][0..3]
    float4 w2b = *(const float4*)&W2[lane * 16 + 4];   // W2[2*lane][4..7]
    float4 w2c = *(const float4*)&W2[lane * 16 + 8];   // W2[2*lane+1][0..3]
    float4 w2d = *(const float4*)&W2[lane * 16 + 12];  // W2[2*lane+1][4..7]

    const bool hi4 = (lane & 4) != 0;
    const bool hi2 = (lane & 2) != 0;
    const bool hi1 = (lane & 1) != 0;

    float2 zx = *(const float2*)&z[(size_t)(R0 + wv * 16) * 128 + lane * 2];
    #pragma unroll 1
    for (int rr = 0; rr < 16; rr++) {
        const int rl = wv * 16 + rr;
        float x0 = zx.x, x1 = zx.y;
        if (rr < 15)
            zx = *(const float2*)&z[(size_t)(R0 + rl + 1) * 128 + lane * 2];

        float s1 = x0 + x1, s2 = x0 * x0 + x1 * x1;
        #pragma unroll
        for (int off = 32; off > 0; off >>= 1) {
            s1 += __shfl_xor(s1, off, 64);
            s2 += __shfl_xor(s2, off, 64);
        }
        float mu  = s1 * (1.0f / 128.0f);
        float var = s2 * (1.0f / 128.0f) - mu * mu;
        float rs  = rsqrtf(var + 1e-5f);
        float mh0 = (x0 - mu) * rs * g2.x + be2.x;
        float mh1 = (x1 - mu) * rs * g2.y + be2.y;

        float p[8];
        p[0] = fmaf(mh0, w2a.x, mh1 * w2c.x);
        p[1] = fmaf(mh0, w2a.y, mh1 * w2c.y);
        p[2] = fmaf(mh0, w2a.z, mh1 * w2c.z);
        p[3] = fmaf(mh0, w2a.w, mh1 * w2c.w);
        p[4] = fmaf(mh0, w2b.x, mh1 * w2d.x);
        p[5] = fmaf(mh0, w2b.y, mh1 * w2d.y);
        p[6] = fmaf(mh0, w2b.z, mh1 * w2d.z);
        p[7] = fmaf(mh0, w2b.w, mh1 * w2d.w);

        // fold: value-split on lane bits 2,1,0 -> h = lane&7
        float t[4];
        #pragma unroll
        for (int k = 0; k < 4; k++) {
            float keep = hi4 ? p[k + 4] : p[k];
            float send = hi4 ? p[k] : p[k + 4];
            t[k] = keep + __shfl_xor(send, 4, 64);
        }
        float u[2];
        #pragma unroll
        for (int k = 0; k < 2; k++) {
            float keep = hi2 ? t[k + 2] : t[k];
            float send = hi2 ? t[k] : t[k + 2];
            u[k] = keep + __shfl_xor(send, 2, 64);
        }
        float vsum;
        {
            float keep = hi1 ? u[1] : u[0];
            float send = hi1 ? u[0] : u[1];
            vsum = keep + __shfl_xor(send, 1, 64);
        }
        vsum += __shfl_xor(vsum, 8, 64);
        vsum += __shfl_xor(vsum, 16, 64);
        vsum += __shfl_xor(vsum, 32, 64);
        if (lane < 8) part[rl][lane] = vsum;   // h = lane
    }
    __syncthreads();

    // write: 512 outputs, thread t writes (h=t>>6, rl=t&63) and (h+4, rl)
    {
        int h0 = tid >> 6, rl = tid & 63;
        b_buf[(size_t)h0 * 147456 + R0 + rl]       = part[rl][h0];
        b_buf[(size_t)(h0 + 4) * 147456 + R0 + rl] = part[rl][h0 + 4];
    }
}

// ---------------------------------------------------------------------------
// k3a: partial online softmax over 16-i chunks. grid = 8*24 = 192, block 128.
__global__ __launch_bounds__(128) void k3a_part(
    const float* __restrict__ w_buf, float* __restrict__ pm, float* __restrict__ pl)
{
    const int h = blockIdx.x / 24, ic = blockIdx.x % 24;
    const int i0 = ic * 16;
    const int tid = threadIdx.x;
    const float* base = w_buf + ((size_t)h * 384 + i0) * 384;

    float m0 = -INFINITY, m1 = -INFINITY, m2 = -INFINITY;
    float l0 = 0.f, l1 = 0.f, l2 = 0.f;
    #pragma unroll 4
    for (int ii = 0; ii < 16; ii++) {
        float x0 = base[ii * 384 + tid];
        float x1 = base[ii * 384 + tid + 128];
        float x2 = base[ii * 384 + tid + 256];
        float n0 = fmaxf(m0, x0);
        l0 = l0 * __expf(m0 - n0) + __expf(x0 - n0); m0 = n0;
        float n1 = fmaxf(m1, x1);
        l1 = l1 * __expf(m1 - n1) + __expf(x1 - n1); m1 = n1;
        float n2 = fmaxf(m2, x2);
        l2 = l2 * __expf(m2 - n2) + __expf(x2 - n2); m2 = n2;
    }
    float* pmb = pm + ((size_t)h * 24 + ic) * 384;
    float* plb = pl + ((size_t)h * 24 + ic) * 384;
    pmb[tid]       = m0;  plb[tid]       = l0;
    pmb[tid + 128] = m1;  plb[tid + 128] = l1;
    pmb[tid + 256] = m2;  plb[tid + 256] = l2;
}

// k3m: combine 24 partials -> M, invL. grid = 8 blocks, 384 threads.
__global__ __launch_bounds__(384) void k3m_comb(
    const float* __restrict__ pm, const float* __restrict__ pl,
    float* __restrict__ Mf, float* __restrict__ invLf)
{
    const int h = blockIdx.x, j = threadIdx.x;
    float M = -INFINITY, L = 0.f;
    #pragma unroll 4
    for (int ic = 0; ic < 24; ic++) {
        float m = pm[((size_t)h * 24 + ic) * 384 + j];
        float l = pl[((size_t)h * 24 + ic) * 384 + j];
        float nM = fmaxf(M, m);
        L = L * __expf(M - nM) + l * __expf(m - nM);
        M = nM;
    }
    Mf[h * 384 + j] = M;
    invLf[h * 384 + j] = 1.0f / L;
}

// k3b: write normalized bf16 weights. grid = 192, block 128.
__global__ __launch_bounds__(128) void k3b_write(
    const float* __restrict__ w_buf, const float* __restrict__ Mf,
    const float* __restrict__ invLf, __hip_bfloat16* __restrict__ w_bf)
{
    const int h = blockIdx.x / 24, ic = blockIdx.x % 24;
    const int i0 = ic * 16;
    const int tid = threadIdx.x;
    const float* base = w_buf + ((size_t)h * 384 + i0) * 384;
    __hip_bfloat16* ob = w_bf + ((size_t)h * 384 + i0) * 384;

    float M0 = Mf[h * 384 + tid],       iL0 = invLf[h * 384 + tid];
    float M1 = Mf[h * 384 + tid + 128], iL1 = invLf[h * 384 + tid + 128];
    float M2 = Mf[h * 384 + tid + 256], iL2 = invLf[h * 384 + tid + 256];
    #pragma unroll 4
    for (int ii = 0; ii < 16; ii++) {
        float x0 = base[ii * 384 + tid];
        float x1 = base[ii * 384 + tid + 128];
        float x2 = base[ii * 384 + tid + 256];
        ob[ii * 384 + tid]       = __float2bfloat16(__expf(x0 - M0) * iL0);
        ob[ii * 384 + tid + 128] = __float2bfloat16(__expf(x1 - M1) * iL1);
        ob[ii * 384 + tid + 256] = __float2bfloat16(__expf(x2 - M2) * iL2);
    }
}

// ---------------------------------------------------------------------------
// k4: MFMA einsum + gate + @W4.  grid = 512*6 = 3072 blocks, 256 threads.
//
// R2 restructure (post-mortem of r1: direct-global B-frags => VGPR-starved
// pipelining => latency serialization at 450us). V goes back to LDS, but:
//  - async global_load_lds (width 16), no VGPR round-trip
//  - double-buffered at HALF-h granularity (16 c-rows = 12288 B/stage):
//    16 phases of { issue stage p+1 ; compute p ; barrier }  (m97 pattern)
//  - LDS dest linear (required by global_load_lds); bank conflicts fixed by
//    XOR-swizzling the GLOBAL source chunk at stage time and the ds_read
//    chunk at use: chunk' = chunk ^ (row&7)  (8 words/bank = minimum)
//  - o_l per-wave private => zero extra barriers; final W4 GEMM unchanged
//  - LDS 2*12288 + 33792 = 58368 B => 2 blocks/CU; launch_bounds(256,2)
//    gives 256 VGPRs so the 12 A-loads/phase fully pipeline.
#define OSTR 264   // LDS o_l stride: 528 B -> superbank step = 33 % 8 = 1

__global__ __launch_bounds__(256, 2) void k4_mfma(
    const __hip_bfloat16* __restrict__ w_bf,   // [8][384][384]
    const __hip_bfloat16* __restrict__ v_tg,   // [512][8][32][384]
    const __hip_bfloat16* __restrict__ g_bf,   // [512][384][256]
    const __hip_bfloat16* __restrict__ W4t,    // [64][256]
    float* __restrict__ out)                   // [512][384][64]
{
    __shared__ short v_t[2][6144];             // 2 x 12288 B (16 rows x 384 j)
    __shared__ short o_l[64 * OSTR];           // 33792 B
    const int bx0 = blockIdx.x;
    const int bx = (bx0 & 7) * 384 + (bx0 >> 3);   // bijective XCD swizzle
    const int s = bx / 6, i0 = (bx % 6) * 64;
    const int tid = threadIdx.x;
    const int lane = tid & 63, wv = tid >> 6;
    const int col = lane & 15, quad = lane >> 4;
    const int swz = col & 7;

    // stage-chunk geometry: chunk p = r*256 + tid ; row = p/48 ;
    // src chunk = (p%48) ^ (row&7)  (inverse swizzle on global source)
    int srow[3], skc[3];
    #pragma unroll
    for (int r = 0; r < 3; r++) {
        int p = r * 256 + tid;
        int row = p / 48;
        srow[r] = row;
        skc[r] = (p - row * 48) ^ (row & 7);
    }

    const short* wA_base = (const short*)w_bf
        + (size_t)(i0 + wv * 16 + col) * 384 + quad * 8;
    const short* vslab = (const short*)v_tg + (size_t)s * 98304;
    const __hip_bfloat16* gbase = g_bf + (size_t)(s * 384 + i0) * 256;
    const int ibase = wv * 16 + quad * 4;

    // issue 3 async 16B DMA per thread: stages 16 c-rows of (h, half)
    auto STAGE = [&](int buf, int h, int half) {
        const short* src = vslab + h * 12288 + half * 6144;
        short* dstb = &v_t[buf][wv * 512];     // wave-uniform base
        #pragma unroll
        for (int r = 0; r < 3; r++) {
            __builtin_amdgcn_global_load_lds(
                (const __attribute__((address_space(1))) u32*)
                    (src + srow[r] * 384 + skc[r] * 8),
                (__attribute__((address_space(3))) u32*)(dstb + r * 2048),
                16, 0, 0);
        }
    };

    // 12 MFMAs over K=384; B-frag row = col (c within the staged half)
    auto COMPUTE = [&](int buf, int h) -> f32x4 {
        f32x4 acc = {0.f, 0.f, 0.f, 0.f};
        const short* wA = wA_base + (size_t)h * 147456;
        #pragma unroll
        for (int ks = 0; ks < 12; ks++) {
            int k0 = ks * 32;
            bf16x8 a = *(const bf16x8*)(wA + k0);
            int ch = (ks * 4 + quad) ^ swz;
            bf16x8 b = *(const bf16x8*)&v_t[buf][col * 384 + ch * 8];
            acc = __builtin_amdgcn_mfma_f32_16x16x32_bf16(a, b, acc, 0, 0, 0);
        }
        return acc;
    };

    STAGE(0, 0, 0);
    __syncthreads();                            // drains vmcnt(0)

    int cur = 0;
    #pragma unroll 1
    for (int h = 0; h < 8; h++) {
        // even phase: compute c=[0,16) of h ; prefetch c=[16,32) of h
        STAGE(cur ^ 1, h, 1);
        float g0[4], g1[4];
        #pragma unroll
        for (int reg = 0; reg < 4; reg++) {     // gate loads hide under MFMA
            int il = ibase + reg;
            g0[reg] = __bfloat162float(gbase[il * 256 + h * 32 + col]);
            g1[reg] = __bfloat162float(gbase[il * 256 + h * 32 + 16 + col]);
        }
        f32x4 acc0 = COMPUTE(cur, h);
        __syncthreads();
        cur ^= 1;

        // odd phase: compute c=[16,32) of h ; prefetch c=[0,16) of h+1
        if (h < 7) STAGE(cur ^ 1, h + 1, 0);
        f32x4 acc1 = COMPUTE(cur, h);
        #pragma unroll
        for (int reg = 0; reg < 4; reg++) {
            int il = ibase + reg;
            __hip_bfloat16 t0 = __float2bfloat16(acc0[reg] * g0[reg]);
            __hip_bfloat16 t1 = __float2bfloat16(acc1[reg] * g1[reg]);
            o_l[il * OSTR + h * 32 + col]      = *(short*)&t0;
            o_l[il * OSTR + h * 32 + 16 + col] = *(short*)&t1;
        }
        __syncthreads();
        cur ^= 1;
    }

    // final: out[64,64] = o_l[64,256] @ W4t^T — o_l rows are per-wave private,
    // no barrier needed (within-wave ds_write->ds_read ordered by lgkmcnt).
    f32x4 acc2[4];
    #pragma unroll
    for (int n = 0; n < 4; n++) acc2[n] = (f32x4){0.f, 0.f, 0.f, 0.f};
    #pragma unroll
    for (int ks = 0; ks < 8; ks++) {
        int k0 = ks * 32;
        bf16x8 a = *(const bf16x8*)&o_l[(wv * 16 + col) * OSTR + k0 + quad * 8];
        #pragma unroll
        for (int n = 0; n < 4; n++) {
            bf16x8 b = *(const bf16x8*)((const short*)W4t
                        + (n * 16 + col) * 256 + k0 + quad * 8);
            acc2[n] = __builtin_amdgcn_mfma_f32_16x16x32_bf16(a, b, acc2[n], 0, 0, 0);
        }
    }
    float* obase = out + (size_t)(s * 384 + i0 + wv * 16 + quad * 4) * 64;
    #pragma unroll
    for (int n = 0; n < 4; n++)
        #pragma unroll
        for (int reg = 0; reg < 4; reg++)
            obase[reg * 64 + n * 16 + col] = acc2[n][reg];
}

// ---------------------------------------------------------------------------
extern "C" void kernel_launch(void* const* d_in, const int* in_sizes, int n_in,
                              void* d_out, int out_size, void* d_ws, size_t ws_size,
                              hipStream_t stream)
{
    const float* m_si    = (const float*)d_in[0];
    const float* z_ij    = (const float*)d_in[1];
    const float* gamma_m = (const float*)d_in[2];
    const float* beta_m  = (const float*)d_in[3];
    const float* W1      = (const float*)d_in[4];
    const float* gamma_z = (const float*)d_in[5];
    const float* beta_z  = (const float*)d_in[6];
    const float* W2      = (const float*)d_in[7];
    const float* W3      = (const float*)d_in[8];
    const float* W4      = (const float*)d_in[9];
    float* out = (float*)d_out;

    // ws layout (~209.0 MB):
    //   g_bf : 100663296 B   v_tg : 100663296 B   w_buf(fp32): 4718592 B
    //   w_bf : 2359296 B     W4t  : 32768 B
    //   pm/pl: 294912 B each   Mf/invLf: 12288 B each
    char* ws = (char*)d_ws;
    __hip_bfloat16* g_bf = (__hip_bfloat16*)ws;
    __hip_bfloat16* v_tg = (__hip_bfloat16*)(ws + 100663296);
    float*          w_buf = (float*)(ws + 201326592);
    __hip_bfloat16* w_bf = (__hip_bfloat16*)(ws + 206045184);
    __hip_bfloat16* W4t  = (__hip_bfloat16*)(ws + 208404480);
    float* pm    = (float*)(ws + 208437248);
    float* pl    = (float*)(ws + 208732160);
    float* Mf    = (float*)(ws + 209027072);
    float* invLf = (float*)(ws + 209039360);

    k0_w4t   <<<64,    256, 0, stream>>>(W4, W4t);
    k1_ln_mv <<<12288, 256, 0, stream>>>(m_si, gamma_m, beta_m, W1, W3, v_tg, g_bf);
    k2_ln_z  <<<2304,  256, 0, stream>>>(z_ij, gamma_z, beta_z, W2, w_buf);
    k3a_part <<<192,   128, 0, stream>>>(w_buf, pm, pl);
    k3m_comb <<<8,     384, 0, stream>>>(pm, pl, Mf, invLf);
    k3b_write<<<192,   128, 0, stream>>>(w_buf, Mf, invLf, w_bf);
    k4_mfma  <<<3072,  256, 0, stream>>>(w_bf, v_tg, g_bf, W4t, out);
}

// Round 3
// 511.368 us; speedup vs baseline: 1.6157x; 1.2371x over previous
//
#include <hip/hip_runtime.h>
#include <hip/hip_bf16.h>
#include <math.h>

// Shapes: B=1, S=512, N=384, c_m=64, c_z=128, H=8, c=32  (HC = 256)
//
// Pipeline:
//  k0_prep: W4[256,64] fp32 -> W4t[64][256] bf16;  W1|W3 -> W13s[512][64] bf16
//           (pre-swizzled: chunk ^= n&7, so k1 can DMA it linearly into LDS)
//  k1     : m = LN(m_si) -> bf16 LDS; MFMA GEMM vs W13 (K=64):
//           v = m@W1 stored TRANSPOSED v_tg[s][hc][j] (operand-swapped MFMA);
//           g = sigmoid(m@W3) -> g_bf[s][j][hc].  128 rows/block.
//  k2     : b = LN(z)@W2 -> w_buf[h][i][j] fp32   (64 rows/block, fold-reduce)
//  k3a    : partial online softmax (m,l) per (h, 16-i-chunk, j)
//  k3m    : combine 24 partials -> M[h][j], invL[h][j]
//  k3b    : w_bf[h][i][j] = bf16( exp(x - M) * invL )
//  k4     : MFMA einsum + gate + @W4, async-pipelined V staging.

typedef __attribute__((ext_vector_type(8))) short bf16x8;   // 8 bf16 = 4 VGPRs
typedef __attribute__((ext_vector_type(4))) float f32x4;
typedef unsigned int u32;

__global__ __launch_bounds__(256) void k0_prep(
    const float* __restrict__ W4, const float* __restrict__ W1,
    const float* __restrict__ W3,
    __hip_bfloat16* __restrict__ W4t,    // [64][256]
    __hip_bfloat16* __restrict__ W13s)   // [512][64] chunk-swizzled
{
    int idx = blockIdx.x * 256 + threadIdx.x;   // 192*256 = 49152
    if (idx < 16384) {
        int d = idx >> 8, k = idx & 255;
        W4t[idx] = __float2bfloat16(W4[k * 64 + d]);
    } else {
        int t = idx - 16384;            // 0..32767
        int n = t >> 6, k = t & 63;
        float v = (n < 256) ? W1[k * 256 + n] : W3[k * 256 + (n - 256)];
        // store logical (n, k) at swizzled chunk (k>>3)^(n&7), elem k&7
        int dst = n * 64 + ((((k >> 3) ^ (n & 7))) << 3) + (k & 7);
        W13s[dst] = __float2bfloat16(v);
    }
}

// ---------------------------------------------------------------------------
// k1: LN + dual GEMM via MFMA. grid = 512*3 = 1536 blocks, 256 threads.
// Block: one s, 128 j-rows. LDS: m̂[128][64] bf16 swizzled (16KB) +
// W13 copy (64KB, swizzled, DMA'd while LN runs). 80KB -> 2 blocks/CU.
__global__ __launch_bounds__(256) void k1_ln_mv(
    const float* __restrict__ m_si,
    const float* __restrict__ gamma_m, const float* __restrict__ beta_m,
    const __hip_bfloat16* __restrict__ W13s, // [512][64] bf16 pre-swizzled
    __hip_bfloat16* __restrict__ v_tg,   // [512][256 hc][384 j]
    __hip_bfloat16* __restrict__ g_bf)   // [512][384 j][256 hc]
{
    __shared__ short a_t[128 * 64];     // 16384 B: m̂, chunk-swizzled
    __shared__ short b_t[512 * 64];     // 65536 B: W13, chunk-swizzled
    const int bx = blockIdx.x;
    const int s = bx / 3, j0 = (bx % 3) * 128;
    const int tid = threadIdx.x;
    const int lane = tid & 63, wv = tid >> 6;
    const int col = lane & 15, quad = lane >> 4;

    // ---- stage W13 into LDS (async DMA; overlaps the LN VALU phase) ----
    {
        const short* src = (const short*)W13s;
        #pragma unroll
        for (int i = 0; i < 16; i++) {
            __builtin_amdgcn_global_load_lds(
                (const __attribute__((address_space(1))) u32*)
                    (src + i * 2048 + wv * 512 + lane * 8),
                (__attribute__((address_space(3))) u32*)(b_t + i * 2048 + wv * 512),
                16, 0, 0);
        }
    }

    // ---- LN: 32 rows per wave, lane = channel; write bf16 m̂ swizzled ----
    {
        const float gm = gamma_m[lane], bm = beta_m[lane];
        const float* mrow = m_si + (size_t)(s * 384 + j0) * 64;
        const int cl = lane >> 3, e = lane & 7;
        #pragma unroll 4
        for (int rr = 0; rr < 32; rr++) {
            int r = wv * 32 + rr;
            float x = mrow[r * 64 + lane];
            float s1 = x, s2 = x * x;
            #pragma unroll
            for (int off = 32; off > 0; off >>= 1) {
                s1 += __shfl_xor(s1, off, 64);
                s2 += __shfl_xor(s2, off, 64);
            }
            float mu  = s1 * (1.0f / 64.0f);
            float var = s2 * (1.0f / 64.0f) - mu * mu;
            float rs  = rsqrtf(var + 1e-5f);
            __hip_bfloat16 mh = __float2bfloat16((x - mu) * rs * gm + bm);
            a_t[r * 64 + ((cl ^ (r & 7)) << 3) + e] = *(short*)&mh;
        }
    }
    __syncthreads();    // drains DMA (vmcnt 0) + LDS writes

    // ---- GEMM: block tile 128 x 512, wave tile 64 x 64 per n-step ----
    const int wm = wv >> 1, wn = wv & 1;

    bf16x8 mf[4][2];    // m̂ A/B-frags, fixed across all n-steps
    #pragma unroll
    for (int mt = 0; mt < 4; mt++) {
        int r = wm * 64 + mt * 16 + col;
        #pragma unroll
        for (int ks = 0; ks < 2; ks++) {
            int c = ks * 4 + quad;
            mf[mt][ks] = *(const bf16x8*)&a_t[r * 64 + ((c ^ (r & 7)) << 3)];
        }
    }

    short* vbase = (short*)v_tg + (size_t)s * 98304;          // [hc][384]
    __hip_bfloat16* gb = g_bf + (size_t)s * 98304;            // [384][256]

    #pragma unroll 1
    for (int step = 0; step < 4; step++) {
        bf16x8 wf[4][2];
        #pragma unroll
        for (int nt = 0; nt < 4; nt++) {
            int n = step * 128 + wn * 64 + nt * 16 + col;
            #pragma unroll
            for (int ks = 0; ks < 2; ks++) {
                int c = ks * 4 + quad;
                wf[nt][ks] = *(const bf16x8*)&b_t[n * 64 + ((c ^ (n & 7)) << 3)];
            }
        }

        if (step < 2) {
            // v half: operand-swapped -> D[n][j], matches v_tg transpose
            f32x4 acc[4][4];
            #pragma unroll
            for (int nt = 0; nt < 4; nt++)
                #pragma unroll
                for (int mt = 0; mt < 4; mt++)
                    acc[nt][mt] = (f32x4){0.f, 0.f, 0.f, 0.f};
            #pragma unroll
            for (int ks = 0; ks < 2; ks++)
                #pragma unroll
                for (int nt = 0; nt < 4; nt++)
                    #pragma unroll
                    for (int mt = 0; mt < 4; mt++)
                        acc[nt][mt] = __builtin_amdgcn_mfma_f32_16x16x32_bf16(
                            wf[nt][ks], mf[mt][ks], acc[nt][mt], 0, 0, 0);
            #pragma unroll
            for (int nt = 0; nt < 4; nt++)
                #pragma unroll
                for (int mt = 0; mt < 4; mt++) {
                    int jg = j0 + wm * 64 + mt * 16 + col;
                    #pragma unroll
                    for (int reg = 0; reg < 4; reg++) {
                        int n = step * 128 + wn * 64 + nt * 16 + quad * 4 + reg;
                        __hip_bfloat16 t = __float2bfloat16(acc[nt][mt][reg]);
                        vbase[n * 384 + jg] = *(short*)&t;
                    }
                }
        } else {
            // g half: normal orientation -> D[j][n], matches g_bf layout
            f32x4 acc[4][4];
            #pragma unroll
            for (int mt = 0; mt < 4; mt++)
                #pragma unroll
                for (int nt = 0; nt < 4; nt++)
                    acc[mt][nt] = (f32x4){0.f, 0.f, 0.f, 0.f};
            #pragma unroll
            for (int ks = 0; ks < 2; ks++)
                #pragma unroll
                for (int mt = 0; mt < 4; mt++)
                    #pragma unroll
                    for (int nt = 0; nt < 4; nt++)
                        acc[mt][nt] = __builtin_amdgcn_mfma_f32_16x16x32_bf16(
                            mf[mt][ks], wf[nt][ks], acc[mt][nt], 0, 0, 0);
            #pragma unroll
            for (int mt = 0; mt < 4; mt++)
                #pragma unroll
                for (int nt = 0; nt < 4; nt++) {
                    int n = (step - 2) * 128 + wn * 64 + nt * 16 + col;
                    #pragma unroll
                    for (int reg = 0; reg < 4; reg++) {
                        int jg = j0 + wm * 64 + mt * 16 + quad * 4 + reg;
                        float gv = 1.0f / (1.0f + __expf(-acc[mt][nt][reg]));
                        gb[(size_t)jg * 256 + n] = __float2bfloat16(gv);
                    }
                }
        }
    }
}

// ---------------------------------------------------------------------------
// k2: 64 rows/block, 4 waves, one wave per row step. grid = 2304.
__global__ __launch_bounds__(256) void k2_ln_z(
    const float* __restrict__ z,
    const float* __restrict__ gamma_z, const float* __restrict__ beta_z,
    const float* __restrict__ W2, float* __restrict__ b_buf)
{
    const int tid = threadIdx.x;
    const int lane = tid & 63, wv = tid >> 6;
    const int R0 = blockIdx.x * 64;
    __shared__ float part[64][9];       // [row_local][h], stride 9 = conflict-free

    // per-lane constants: k-pair 2*lane, 2*lane+1
    float2 g2 = *(const float2*)&gamma_z[lane * 2];
    float2 be2 = *(const float2*)&beta_z[lane * 2];
    float4 w2a = *(const float4*)&W2[lane * 16];       // W2[2*lane][0..3]
    float4 w2b = *(const float4*)&W2[lane * 16 + 4];   // W2[2*lane][4..7]
    float4 w2c = *(const float4*)&W2[lane * 16 + 8];   // W2[2*lane+1][0..3]
    float4 w2d = *(const float4*)&W2[lane * 16 + 12];  // W2[2*lane+1][4..7]

    const bool hi4 = (lane & 4) != 0;
    const bool hi2 = (lane & 2) != 0;
    const bool hi1 = (lane & 1) != 0;

    float2 zx = *(const float2*)&z[(size_t)(R0 + wv * 16) * 128 + lane * 2];
    #pragma unroll 1
    for (int rr = 0; rr < 16; rr++) {
        const int rl = wv * 16 + rr;
        float x0 = zx.x, x1 = zx.y;
        if (rr < 15)
            zx = *(const float2*)&z[(size_t)(R0 + rl + 1) * 128 + lane * 2];

        float s1 = x0 + x1, s2 = x0 * x0 + x1 * x1;
        #pragma unroll
        for (int off = 32; off > 0; off >>= 1) {
            s1 += __shfl_xor(s1, off, 64);
            s2 += __shfl_xor(s2, off, 64);
        }
        float mu  = s1 * (1.0f / 128.0f);
        float var = s2 * (1.0f / 128.0f) - mu * mu;
        float rs  = rsqrtf(var + 1e-5f);
        float mh0 = (x0 - mu) * rs * g2.x + be2.x;
        float mh1 = (x1 - mu) * rs * g2.y + be2.y;

        float p[8];
        p[0] = fmaf(mh0, w2a.x, mh1 * w2c.x);
        p[1] = fmaf(mh0, w2a.y, mh1 * w2c.y);
        p[2] = fmaf(mh0, w2a.z, mh1 * w2c.z);
        p[3] = fmaf(mh0, w2a.w, mh1 * w2c.w);
        p[4] = fmaf(mh0, w2b.x, mh1 * w2d.x);
        p[5] = fmaf(mh0, w2b.y, mh1 * w2d.y);
        p[6] = fmaf(mh0, w2b.z, mh1 * w2d.z);
        p[7] = fmaf(mh0, w2b.w, mh1 * w2d.w);

        // fold: value-split on lane bits 2,1,0 -> h = lane&7
        float t[4];
        #pragma unroll
        for (int k = 0; k < 4; k++) {
            float keep = hi4 ? p[k + 4] : p[k];
            float send = hi4 ? p[k] : p[k + 4];
            t[k] = keep + __shfl_xor(send, 4, 64);
        }
        float u[2];
        #pragma unroll
        for (int k = 0; k < 2; k++) {
            float keep = hi2 ? t[k + 2] : t[k];
            float send = hi2 ? t[k] : t[k + 2];
            u[k] = keep + __shfl_xor(send, 2, 64);
        }
        float vsum;
        {
            float keep = hi1 ? u[1] : u[0];
            float send = hi1 ? u[0] : u[1];
            vsum = keep + __shfl_xor(send, 1, 64);
        }
        vsum += __shfl_xor(vsum, 8, 64);
        vsum += __shfl_xor(vsum, 16, 64);
        vsum += __shfl_xor(vsum, 32, 64);
        if (lane < 8) part[rl][lane] = vsum;   // h = lane
    }
    __syncthreads();

    // write: 512 outputs, thread t writes (h=t>>6, rl=t&63) and (h+4, rl)
    {
        int h0 = tid >> 6, rl = tid & 63;
        b_buf[(size_t)h0 * 147456 + R0 + rl]       = part[rl][h0];
        b_buf[(size_t)(h0 + 4) * 147456 + R0 + rl] = part[rl][h0 + 4];
    }
}

// ---------------------------------------------------------------------------
// k3a: partial online softmax over 16-i chunks. grid = 8*24 = 192, block 128.
__global__ __launch_bounds__(128) void k3a_part(
    const float* __restrict__ w_buf, float* __restrict__ pm, float* __restrict__ pl)
{
    const int h = blockIdx.x / 24, ic = blockIdx.x % 24;
    const int i0 = ic * 16;
    const int tid = threadIdx.x;
    const float* base = w_buf + ((size_t)h * 384 + i0) * 384;

    float m0 = -INFINITY, m1 = -INFINITY, m2 = -INFINITY;
    float l0 = 0.f, l1 = 0.f, l2 = 0.f;
    #pragma unroll 4
    for (int ii = 0; ii < 16; ii++) {
        float x0 = base[ii * 384 + tid];
        float x1 = base[ii * 384 + tid + 128];
        float x2 = base[ii * 384 + tid + 256];
        float n0 = fmaxf(m0, x0);
        l0 = l0 * __expf(m0 - n0) + __expf(x0 - n0); m0 = n0;
        float n1 = fmaxf(m1, x1);
        l1 = l1 * __expf(m1 - n1) + __expf(x1 - n1); m1 = n1;
        float n2 = fmaxf(m2, x2);
        l2 = l2 * __expf(m2 - n2) + __expf(x2 - n2); m2 = n2;
    }
    float* pmb = pm + ((size_t)h * 24 + ic) * 384;
    float* plb = pl + ((size_t)h * 24 + ic) * 384;
    pmb[tid]       = m0;  plb[tid]       = l0;
    pmb[tid + 128] = m1;  plb[tid + 128] = l1;
    pmb[tid + 256] = m2;  plb[tid + 256] = l2;
}

// k3m: combine 24 partials -> M, invL. grid = 8 blocks, 384 threads.
__global__ __launch_bounds__(384) void k3m_comb(
    const float* __restrict__ pm, const float* __restrict__ pl,
    float* __restrict__ Mf, float* __restrict__ invLf)
{
    const int h = blockIdx.x, j = threadIdx.x;
    float M = -INFINITY, L = 0.f;
    #pragma unroll 4
    for (int ic = 0; ic < 24; ic++) {
        float m = pm[((size_t)h * 24 + ic) * 384 + j];
        float l = pl[((size_t)h * 24 + ic) * 384 + j];
        float nM = fmaxf(M, m);
        L = L * __expf(M - nM) + l * __expf(m - nM);
        M = nM;
    }
    Mf[h * 384 + j] = M;
    invLf[h * 384 + j] = 1.0f / L;
}

// k3b: write normalized bf16 weights. grid = 192, block 128.
__global__ __launch_bounds__(128) void k3b_write(
    const float* __restrict__ w_buf, const float* __restrict__ Mf,
    const float* __restrict__ invLf, __hip_bfloat16* __restrict__ w_bf)
{
    const int h = blockIdx.x / 24, ic = blockIdx.x % 24;
    const int i0 = ic * 16;
    const int tid = threadIdx.x;
    const float* base = w_buf + ((size_t)h * 384 + i0) * 384;
    __hip_bfloat16* ob = w_bf + ((size_t)h * 384 + i0) * 384;

    float M0 = Mf[h * 384 + tid],       iL0 = invLf[h * 384 + tid];
    float M1 = Mf[h * 384 + tid + 128], iL1 = invLf[h * 384 + tid + 128];
    float M2 = Mf[h * 384 + tid + 256], iL2 = invLf[h * 384 + tid + 256];
    #pragma unroll 4
    for (int ii = 0; ii < 16; ii++) {
        float x0 = base[ii * 384 + tid];
        float x1 = base[ii * 384 + tid + 128];
        float x2 = base[ii * 384 + tid + 256];
        ob[ii * 384 + tid]       = __float2bfloat16(__expf(x0 - M0) * iL0);
        ob[ii * 384 + tid + 128] = __float2bfloat16(__expf(x1 - M1) * iL1);
        ob[ii * 384 + tid + 256] = __float2bfloat16(__expf(x2 - M2) * iL2);
    }
}

// ---------------------------------------------------------------------------
// k4: MFMA einsum + gate + @W4.  grid = 512*6 = 3072 blocks, 256 threads.
// (unchanged from R2: async global_load_lds double-buffer at half-h
//  granularity, swizzled source, per-wave-private o_l, XCD swizzle)
#define OSTR 264   // LDS o_l stride: 528 B -> superbank step = 33 % 8 = 1

__global__ __launch_bounds__(256, 2) void k4_mfma(
    const __hip_bfloat16* __restrict__ w_bf,   // [8][384][384]
    const __hip_bfloat16* __restrict__ v_tg,   // [512][8][32][384]
    const __hip_bfloat16* __restrict__ g_bf,   // [512][384][256]
    const __hip_bfloat16* __restrict__ W4t,    // [64][256]
    float* __restrict__ out)                   // [512][384][64]
{
    __shared__ short v_t[2][6144];             // 2 x 12288 B (16 rows x 384 j)
    __shared__ short o_l[64 * OSTR];           // 33792 B
    const int bx0 = blockIdx.x;
    const int bx = (bx0 & 7) * 384 + (bx0 >> 3);   // bijective XCD swizzle
    const int s = bx / 6, i0 = (bx % 6) * 64;
    const int tid = threadIdx.x;
    const int lane = tid & 63, wv = tid >> 6;
    const int col = lane & 15, quad = lane >> 4;
    const int swz = col & 7;

    int srow[3], skc[3];
    #pragma unroll
    for (int r = 0; r < 3; r++) {
        int p = r * 256 + tid;
        int row = p / 48;
        srow[r] = row;
        skc[r] = (p - row * 48) ^ (row & 7);
    }

    const short* wA_base = (const short*)w_bf
        + (size_t)(i0 + wv * 16 + col) * 384 + quad * 8;
    const short* vslab = (const short*)v_tg + (size_t)s * 98304;
    const __hip_bfloat16* gbase = g_bf + (size_t)(s * 384 + i0) * 256;
    const int ibase = wv * 16 + quad * 4;

    auto STAGE = [&](int buf, int h, int half) {
        const short* src = vslab + h * 12288 + half * 6144;
        short* dstb = &v_t[buf][wv * 512];     // wave-uniform base
        #pragma unroll
        for (int r = 0; r < 3; r++) {
            __builtin_amdgcn_global_load_lds(
                (const __attribute__((address_space(1))) u32*)
                    (src + srow[r] * 384 + skc[r] * 8),
                (__attribute__((address_space(3))) u32*)(dstb + r * 2048),
                16, 0, 0);
        }
    };

    auto COMPUTE = [&](int buf, int h) -> f32x4 {
        f32x4 acc = {0.f, 0.f, 0.f, 0.f};
        const short* wA = wA_base + (size_t)h * 147456;
        #pragma unroll
        for (int ks = 0; ks < 12; ks++) {
            int k0 = ks * 32;
            bf16x8 a = *(const bf16x8*)(wA + k0);
            int ch = (ks * 4 + quad) ^ swz;
            bf16x8 b = *(const bf16x8*)&v_t[buf][col * 384 + ch * 8];
            acc = __builtin_amdgcn_mfma_f32_16x16x32_bf16(a, b, acc, 0, 0, 0);
        }
        return acc;
    };

    STAGE(0, 0, 0);
    __syncthreads();                            // drains vmcnt(0)

    int cur = 0;
    #pragma unroll 1
    for (int h = 0; h < 8; h++) {
        STAGE(cur ^ 1, h, 1);
        float g0[4], g1[4];
        #pragma unroll
        for (int reg = 0; reg < 4; reg++) {     // gate loads hide under MFMA
            int il = ibase + reg;
            g0[reg] = __bfloat162float(gbase[il * 256 + h * 32 + col]);
            g1[reg] = __bfloat162float(gbase[il * 256 + h * 32 + 16 + col]);
        }
        f32x4 acc0 = COMPUTE(cur, h);
        __syncthreads();
        cur ^= 1;

        if (h < 7) STAGE(cur ^ 1, h + 1, 0);
        f32x4 acc1 = COMPUTE(cur, h);
        #pragma unroll
        for (int reg = 0; reg < 4; reg++) {
            int il = ibase + reg;
            __hip_bfloat16 t0 = __float2bfloat16(acc0[reg] * g0[reg]);
            __hip_bfloat16 t1 = __float2bfloat16(acc1[reg] * g1[reg]);
            o_l[il * OSTR + h * 32 + col]      = *(short*)&t0;
            o_l[il * OSTR + h * 32 + 16 + col] = *(short*)&t1;
        }
        __syncthreads();
        cur ^= 1;
    }

    f32x4 acc2[4];
    #pragma unroll
    for (int n = 0; n < 4; n++) acc2[n] = (f32x4){0.f, 0.f, 0.f, 0.f};
    #pragma unroll
    for (int ks = 0; ks < 8; ks++) {
        int k0 = ks * 32;
        bf16x8 a = *(const bf16x8*)&o_l[(wv * 16 + col) * OSTR + k0 + quad * 8];
        #pragma unroll
        for (int n = 0; n < 4; n++) {
            bf16x8 b = *(const bf16x8*)((const short*)W4t
                        + (n * 16 + col) * 256 + k0 + quad * 8);
            acc2[n] = __builtin_amdgcn_mfma_f32_16x16x32_bf16(a, b, acc2[n], 0, 0, 0);
        }
    }
    float* obase = out + (size_t)(s * 384 + i0 + wv * 16 + quad * 4) * 64;
    #pragma unroll
    for (int n = 0; n < 4; n++)
        #pragma unroll
        for (int reg = 0; reg < 4; reg++)
            obase[reg * 64 + n * 16 + col] = acc2[n][reg];
}

// ---------------------------------------------------------------------------
extern "C" void kernel_launch(void* const* d_in, const int* in_sizes, int n_in,
                              void* d_out, int out_size, void* d_ws, size_t ws_size,
                              hipStream_t stream)
{
    const float* m_si    = (const float*)d_in[0];
    const float* z_ij    = (const float*)d_in[1];
    const float* gamma_m = (const float*)d_in[2];
    const float* beta_m  = (const float*)d_in[3];
    const float* W1      = (const float*)d_in[4];
    const float* gamma_z = (const float*)d_in[5];
    const float* beta_z  = (const float*)d_in[6];
    const float* W2      = (const float*)d_in[7];
    const float* W3      = (const float*)d_in[8];
    const float* W4      = (const float*)d_in[9];
    float* out = (float*)d_out;

    // ws layout (~209.0 MB):
    //   g_bf : 100663296 B   v_tg : 100663296 B   w_buf(fp32): 4718592 B
    //   w_bf : 2359296 B     W4t  : 32768 B
    //   pm/pl: 294912 B each   Mf/invLf: 12288 B each
    //   W13s : 65536 B, ALIASES w_buf (dead until k2; k1 reads before k2 writes)
    char* ws = (char*)d_ws;
    __hip_bfloat16* g_bf = (__hip_bfloat16*)ws;
    __hip_bfloat16* v_tg = (__hip_bfloat16*)(ws + 100663296);
    float*          w_buf = (float*)(ws + 201326592);
    __hip_bfloat16* W13s = (__hip_bfloat16*)(ws + 201326592);  // alias w_buf
    __hip_bfloat16* w_bf = (__hip_bfloat16*)(ws + 206045184);
    __hip_bfloat16* W4t  = (__hip_bfloat16*)(ws + 208404480);
    float* pm    = (float*)(ws + 208437248);
    float* pl    = (float*)(ws + 208732160);
    float* Mf    = (float*)(ws + 209027072);
    float* invLf = (float*)(ws + 209039360);

    k0_prep  <<<192,  256, 0, stream>>>(W4, W1, W3, W4t, W13s);
    k1_ln_mv <<<1536, 256, 0, stream>>>(m_si, gamma_m, beta_m, W13s, v_tg, g_bf);
    k2_ln_z  <<<2304, 256, 0, stream>>>(z_ij, gamma_z, beta_z, W2, w_buf);
    k3a_part <<<192,  128, 0, stream>>>(w_buf, pm, pl);
    k3m_comb <<<8,    384, 0, stream>>>(pm, pl, Mf, invLf);
    k3b_write<<<192,  128, 0, stream>>>(w_buf, Mf, invLf, w_bf);
    k4_mfma  <<<3072, 256, 0, stream>>>(w_bf, v_tg, g_bf, W4t, out);
}